// Round 1
// baseline (150.082 us; speedup 1.0000x reference)
//
#include <hip/hip_runtime.h>

// Problem constants (batch: (3, 1280, 1280) fp32, PATCH=16)
#define PS 16
#define HW 1280
#define NPS 80            // patches per side (1280/16)
#define NP (NPS * NPS)    // 6400 patches
#define GSTRIDE 12        // floats per patch record: 9 gram + 1 sq + 2 pad (48B, float4-aligned)

// ---- ordered-uint mapping for float atomic min/max ----
__device__ __forceinline__ unsigned f2ord(float f) {
    unsigned u = __float_as_uint(f);
    return (u & 0x80000000u) ? ~u : (u | 0x80000000u);
}
__device__ __forceinline__ float ord2f(unsigned m) {
    return (m & 0x80000000u) ? __uint_as_float(m & 0x7FFFFFFFu) : __uint_as_float(~m);
}

__global__ void init_mm(unsigned* __restrict__ mm) {
    mm[0] = 0xFFFFFFFFu;  // min identity (maps to +largest)
    mm[1] = 0u;           // max identity
}

// One block (256 threads) per patch: thread t -> (r = t>>4, c = t&15).
// Computes 3x3 gram / 768 and sq = sum(G^2), stores 12-float record.
__global__ __launch_bounds__(256) void gram_kernel(const float* __restrict__ x,
                                                   float* __restrict__ G) {
    const int n = blockIdx.x;
    const int pi = n / NPS, pj = n % NPS;
    const int t = threadIdx.x;
    const int r = t >> 4, c = t & 15;
    const size_t base = (size_t)(pi * PS + r) * HW + (size_t)pj * PS + c;
    const float a0 = x[base];
    const float a1 = x[base + (size_t)HW * HW];
    const float a2 = x[base + 2u * (size_t)HW * HW];
    float p[6] = {a0 * a0, a0 * a1, a0 * a2, a1 * a1, a1 * a2, a2 * a2};
#pragma unroll
    for (int k = 0; k < 6; ++k) {
        float v = p[k];
#pragma unroll
        for (int off = 32; off; off >>= 1) v += __shfl_xor(v, off);
        p[k] = v;
    }
    __shared__ float part[4][6];
    const int wave = t >> 6;
    if ((t & 63) == 0) {
#pragma unroll
        for (int k = 0; k < 6; ++k) part[wave][k] = p[k];
    }
    __syncthreads();
    if (t == 0) {
        float g[6];
#pragma unroll
        for (int k = 0; k < 6; ++k)
            g[k] = (part[0][k] + part[1][k] + part[2][k] + part[3][k]) * (1.0f / 768.0f);
        const float row[9] = {g[0], g[1], g[2], g[1], g[3], g[4], g[2], g[4], g[5]};
        float s = 0.f;
        float* dst = G + (size_t)n * GSTRIDE;
#pragma unroll
        for (int k = 0; k < 9; ++k) { dst[k] = row[k]; s = fmaf(row[k], row[k], s); }
        dst[9] = s;
        dst[10] = 0.f;
        dst[11] = 0.f;
    }
}

// Min/max over all N^2 distances; no stores of the matrix.
// grid (NP/32, 5): block handles 32 rows x 1280 cols.
#define MM_ROWS 32
__global__ __launch_bounds__(256) void minmax_kernel(const float* __restrict__ G,
                                                     unsigned* __restrict__ mm) {
    __shared__ float rg[MM_ROWS][GSTRIDE];
    const int t = threadIdx.x;
    const int r0 = blockIdx.x * MM_ROWS;
    for (int k = t; k < MM_ROWS * GSTRIDE; k += 256)
        rg[k / GSTRIDE][k % GSTRIDE] = G[(size_t)r0 * GSTRIDE + k];
    __syncthreads();
    float vmin = 3.4e38f, vmax = -3.4e38f;
    const int j0 = blockIdx.y * 1280;
    for (int it = 0; it < 5; ++it) {
        const int j = j0 + it * 256 + t;
        const float4 q0 = *(const float4*)(G + (size_t)j * GSTRIDE);
        const float4 q1 = *(const float4*)(G + (size_t)j * GSTRIDE + 4);
        const float4 q2 = *(const float4*)(G + (size_t)j * GSTRIDE + 8);
        const float gj[9] = {q0.x, q0.y, q0.z, q0.w, q1.x, q1.y, q1.z, q1.w, q2.x};
        const float sj = q2.y;
#pragma unroll
        for (int r = 0; r < MM_ROWS; ++r) {
            float inner = 0.f;
#pragma unroll
            for (int k = 0; k < 9; ++k) inner = fmaf(rg[r][k], gj[k], inner);
            const float d = rg[r][9] + sj - 2.f * inner;
            vmin = fminf(vmin, d);
            vmax = fmaxf(vmax, d);
        }
    }
#pragma unroll
    for (int off = 32; off; off >>= 1) {
        vmin = fminf(vmin, __shfl_xor(vmin, off));
        vmax = fmaxf(vmax, __shfl_xor(vmax, off));
    }
    if ((t & 63) == 0) {
        atomicMin(mm, f2ord(vmin));
        atomicMax(mm + 1, f2ord(vmax));
    }
}

// Normalized write: grid (NP/16, 5): block handles 16 rows x 1280 cols.
#define W_ROWS 16
__global__ __launch_bounds__(256) void write_kernel(const float* __restrict__ G,
                                                    const unsigned* __restrict__ mm,
                                                    float* __restrict__ out) {
    __shared__ float rg[W_ROWS][GSTRIDE];
    const int t = threadIdx.x;
    const int r0 = blockIdx.x * W_ROWS;
    for (int k = t; k < W_ROWS * GSTRIDE; k += 256)
        rg[k / GSTRIDE][k % GSTRIDE] = G[(size_t)r0 * GSTRIDE + k];
    __syncthreads();
    const float mn = ord2f(mm[0]);
    const float mx = ord2f(mm[1]);
    const float inv = 1.f / (mx - mn);
    const int j0 = blockIdx.y * 1280;
    for (int it = 0; it < 5; ++it) {
        const int j = j0 + it * 256 + t;
        const float4 q0 = *(const float4*)(G + (size_t)j * GSTRIDE);
        const float4 q1 = *(const float4*)(G + (size_t)j * GSTRIDE + 4);
        const float4 q2 = *(const float4*)(G + (size_t)j * GSTRIDE + 8);
        const float gj[9] = {q0.x, q0.y, q0.z, q0.w, q1.x, q1.y, q1.z, q1.w, q2.x};
        const float sj = q2.y;
#pragma unroll
        for (int r = 0; r < W_ROWS; ++r) {
            float inner = 0.f;
#pragma unroll
            for (int k = 0; k < 9; ++k) inner = fmaf(rg[r][k], gj[k], inner);
            const float d = rg[r][9] + sj - 2.f * inner;
            out[(size_t)(r0 + r) * NP + j] = (d - mn) * inv;
        }
    }
}

extern "C" void kernel_launch(void* const* d_in, const int* in_sizes, int n_in,
                              void* d_out, int out_size, void* d_ws, size_t ws_size,
                              hipStream_t stream) {
    (void)in_sizes; (void)n_in; (void)out_size; (void)ws_size;
    const float* x = (const float*)d_in[0];
    float* out = (float*)d_out;
    float* G = (float*)d_ws;                                       // NP*12 floats = 300 KiB
    unsigned* mm = (unsigned*)((char*)d_ws + (size_t)NP * GSTRIDE * sizeof(float));

    init_mm<<<1, 1, 0, stream>>>(mm);
    gram_kernel<<<NP, 256, 0, stream>>>(x, G);
    minmax_kernel<<<dim3(NP / MM_ROWS, 5), 256, 0, stream>>>(G, mm);
    write_kernel<<<dim3(NP / W_ROWS, 5), 256, 0, stream>>>(G, mm, out);
}

// Round 2
// 85.878 us; speedup vs baseline: 1.7476x; 1.7476x over previous
//
#include <hip/hip_runtime.h>

// Problem constants (batch: (3, 1280, 1280) fp32, PATCH=16)
#define PS 16
#define HW 1280
#define NPS 80            // patches per side (1280/16)
#define NP (NPS * NPS)    // 6400 patches
#define GS 12             // floats per patch record: 9 gram + 1 sq + 2 pad (48B)

// ---- ordered-uint mapping for float atomic min/max ----
__device__ __forceinline__ unsigned f2ord(float f) {
    unsigned u = __float_as_uint(f);
    return (u & 0x80000000u) ? ~u : (u | 0x80000000u);
}
__device__ __forceinline__ float ord2f(unsigned m) {
    return (m & 0x80000000u) ? __uint_as_float(m & 0x7FFFFFFFu) : __uint_as_float(~m);
}

__global__ void init_mm(unsigned* __restrict__ mm) {
    mm[0] = 0xFFFFFFFFu;  // min identity
    mm[1] = 0u;           // max identity
}

// One block (256 threads) per patch: thread t -> (r = t>>4, c = t&15).
// Computes 3x3 gram / 768 and sq = sum(G^2), stores 12-float record.
__global__ __launch_bounds__(256) void gram_kernel(const float* __restrict__ x,
                                                   float* __restrict__ G) {
    const int n = blockIdx.x;
    const int pi = n / NPS, pj = n % NPS;
    const int t = threadIdx.x;
    const int r = t >> 4, c = t & 15;
    const size_t base = (size_t)(pi * PS + r) * HW + (size_t)pj * PS + c;
    const float a0 = x[base];
    const float a1 = x[base + (size_t)HW * HW];
    const float a2 = x[base + 2u * (size_t)HW * HW];
    float p[6] = {a0 * a0, a0 * a1, a0 * a2, a1 * a1, a1 * a2, a2 * a2};
#pragma unroll
    for (int k = 0; k < 6; ++k) {
        float v = p[k];
#pragma unroll
        for (int off = 32; off; off >>= 1) v += __shfl_xor(v, off);
        p[k] = v;
    }
    __shared__ float part[4][6];
    const int wave = t >> 6;
    if ((t & 63) == 0) {
#pragma unroll
        for (int k = 0; k < 6; ++k) part[wave][k] = p[k];
    }
    __syncthreads();
    if (t == 0) {
        float g[6];
#pragma unroll
        for (int k = 0; k < 6; ++k)
            g[k] = (part[0][k] + part[1][k] + part[2][k] + part[3][k]) * (1.0f / 768.0f);
        const float row[9] = {g[0], g[1], g[2], g[1], g[3], g[4], g[2], g[4], g[5]};
        float s = 0.f;
        float* dst = G + (size_t)n * GS;
#pragma unroll
        for (int k = 0; k < 9; ++k) { dst[k] = row[k]; s = fmaf(row[k], row[k], s); }
        dst[9] = s;
        dst[10] = 0.f;
        dst[11] = 0.f;
    }
}

// Min/max over all N^2 distances.
// grid (NP/RT_M, NP/256): lane owns j-record in VGPRs; i-records are
// wave-uniform -> scalar loads. Pure-FMA inner loop, no LDS in the loop.
#define RT_M 128
__global__ __launch_bounds__(256) void minmax_kernel(const float* __restrict__ G,
                                                     unsigned* __restrict__ mm) {
    const int t = threadIdx.x;
    const int j = blockIdx.y * 256 + t;
    const int i0 = blockIdx.x * RT_M;
    const float4 q0 = *(const float4*)(G + (size_t)j * GS);
    const float4 q1 = *(const float4*)(G + (size_t)j * GS + 4);
    const float4 q2 = *(const float4*)(G + (size_t)j * GS + 8);
    const float gj[9] = {q0.x, q0.y, q0.z, q0.w, q1.x, q1.y, q1.z, q1.w, q2.x};
    const float sj = q2.y;
    float vmin = 3.4e38f, vmax = -3.4e38f;
#pragma unroll 8
    for (int r = 0; r < RT_M; ++r) {
        const float* __restrict__ gi = G + (size_t)(i0 + r) * GS;  // uniform -> s_load
        float inner = 0.f;
#pragma unroll
        for (int k = 0; k < 9; ++k) inner = fmaf(gi[k], gj[k], inner);
        const float d = gi[9] + sj - 2.f * inner;
        vmin = fminf(vmin, d);
        vmax = fmaxf(vmax, d);
    }
#pragma unroll
    for (int off = 32; off; off >>= 1) {
        vmin = fminf(vmin, __shfl_xor(vmin, off));
        vmax = fmaxf(vmax, __shfl_xor(vmax, off));
    }
    __shared__ float smin[4], smax[4];
    const int wave = t >> 6;
    if ((t & 63) == 0) { smin[wave] = vmin; smax[wave] = vmax; }
    __syncthreads();
    if (t == 0) {
        float bmin = fminf(fminf(smin[0], smin[1]), fminf(smin[2], smin[3]));
        float bmax = fmaxf(fmaxf(smax[0], smax[1]), fmaxf(smax[2], smax[3]));
        atomicMin(mm, f2ord(bmin));
        atomicMax(mm + 1, f2ord(bmax));
    }
}

// Normalized write. grid (NP/RT_W, NP/256). Same structure: j-record in
// VGPRs per lane, i-records via scalar loads, coalesced 1KB row stores.
#define RT_W 16
__global__ __launch_bounds__(256) void write_kernel(const float* __restrict__ G,
                                                    const unsigned* __restrict__ mm,
                                                    float* __restrict__ out) {
    const int t = threadIdx.x;
    const int j = blockIdx.y * 256 + t;
    const int i0 = blockIdx.x * RT_W;
    const float4 q0 = *(const float4*)(G + (size_t)j * GS);
    const float4 q1 = *(const float4*)(G + (size_t)j * GS + 4);
    const float4 q2 = *(const float4*)(G + (size_t)j * GS + 8);
    const float gj[9] = {q0.x, q0.y, q0.z, q0.w, q1.x, q1.y, q1.z, q1.w, q2.x};
    const float sj = q2.y;
    const float mn = ord2f(mm[0]);
    const float mx = ord2f(mm[1]);
    const float inv = 1.f / (mx - mn);
#pragma unroll
    for (int r = 0; r < RT_W; ++r) {
        const float* __restrict__ gi = G + (size_t)(i0 + r) * GS;  // uniform -> s_load
        float inner = 0.f;
#pragma unroll
        for (int k = 0; k < 9; ++k) inner = fmaf(gi[k], gj[k], inner);
        const float d = gi[9] + sj - 2.f * inner;
        out[(size_t)(i0 + r) * NP + j] = (d - mn) * inv;
    }
}

extern "C" void kernel_launch(void* const* d_in, const int* in_sizes, int n_in,
                              void* d_out, int out_size, void* d_ws, size_t ws_size,
                              hipStream_t stream) {
    (void)in_sizes; (void)n_in; (void)out_size; (void)ws_size;
    const float* x = (const float*)d_in[0];
    float* out = (float*)d_out;
    float* G = (float*)d_ws;                                       // NP*12 floats = 300 KiB
    unsigned* mm = (unsigned*)((char*)d_ws + (size_t)NP * GS * sizeof(float));

    init_mm<<<1, 1, 0, stream>>>(mm);
    gram_kernel<<<NP, 256, 0, stream>>>(x, G);
    minmax_kernel<<<dim3(NP / RT_M, NP / 256), 256, 0, stream>>>(G, mm);
    write_kernel<<<dim3(NP / RT_W, NP / 256), 256, 0, stream>>>(G, mm, out);
}